// Round 4
// baseline (53.706 us; speedup 1.0000x reference)
//
#include <hip/hip_runtime.h>
#include <hip/hip_bf16.h>

#define D_N 512
#define M_N 1024
#define F_N 64
#define L2E 1.442695041f
#define GRID_B 128

__device__ __forceinline__ float wred_sum(float p) {
#pragma unroll
    for (int off = 32; off > 0; off >>= 1) p += __shfl_xor(p, off, 64);
    return p;
}

// device-scope grid barrier: one arrival per block, thread 0 spins.
__device__ __forceinline__ void gbar(int* slot) {
    __syncthreads();
    if (threadIdx.x == 0) {
        __threadfence();
        __hip_atomic_fetch_add(slot, 1, __ATOMIC_ACQ_REL, __HIP_MEMORY_SCOPE_AGENT);
        int spins = 0;
        while (__hip_atomic_load(slot, __ATOMIC_ACQUIRE, __HIP_MEMORY_SCOPE_AGENT) < GRID_B) {
            if (++spins > (1 << 24)) break;   // safety bail (never hit in practice)
            __builtin_amdgcn_s_sleep(1);
        }
        __threadfence();
    }
    __syncthreads();
}

// ---------------------------------------------------------------------------
// One persistent kernel, 128 blocks x 256 threads.
// ws int region: bar0, bar1, done  (zeroed by memset node each call)
// ---------------------------------------------------------------------------
__global__ __launch_bounds__(256) void k_all(
    const int* __restrict__ c_it, const int* __restrict__ m_it,
    const float* __restrict__ c_emb, const float* __restrict__ m_emb,
    const float* __restrict__ pe0, const float* __restrict__ pe1,
    const float* __restrict__ conv_w, const float* __restrict__ conv_b,
    const float* __restrict__ gat_w, const float* __restrict__ gat_b,
    const float* __restrict__ gat_att, const float* __restrict__ hattr,
    const float* __restrict__ lin_w,
    int* __restrict__ bar,            // 3 ints
    float* __restrict__ xw, float* __restrict__ u, float* __restrict__ w2g,
    float* __restrict__ vS, float* __restrict__ c1f, float* __restrict__ c2f,
    float* __restrict__ w1a_g, float* __restrict__ w2a_g,
    float* __restrict__ pp, float* __restrict__ ps,
    float* __restrict__ out)
{
    __shared__ float sWt[64 * 65];                    // sWt[j*65+k] = W[k][j]
    __shared__ float sEdgeV[512], sEdgeC1[512], sEdgeC2[512];
    __shared__ float redA[4][64], redB[4][64];
    __shared__ float sGA[8], sGB[8];
    __shared__ float sS1[64], sS2[64], sP0[64], sP1[64], sMC[64], sMM[64];
    __shared__ float sRepD[128], sRepM[128];
    __shared__ int sIsLast;

    const int b = blockIdx.x, tid = threadIdx.x;
    const int w = tid >> 6, lane = tid & 63;

    // ---------------- Phase 1a: partial gathers (blocks 0..95) -------------
    // pp layout: P0 [0,32), MC [32,64), P1 [64,128), MM [128,192)  (each x64)
    if (b < 96) {
        const int* idx; const float* ta; const float* tb;
        int base_r, oA, oB;
        if (b < 32) { idx = c_it; ta = pe0; tb = c_emb; base_r = b * 16; oA = b; oB = 32 + b; }
        else { int b2 = b - 32; idx = m_it; ta = pe1; tb = m_emb; base_r = b2 * 16; oA = 64 + b2; oB = 128 + b2; }
        const int r0 = base_r + w * 4;
        float a = 0.f, bb = 0.f;
#pragma unroll
        for (int j = 0; j < 4; ++j) {
            int r = idx[r0 + j];
            a  += ta[(size_t)r * F_N + lane];
            bb += tb[(size_t)r * F_N + lane];
        }
        redA[w][lane] = a; redB[w][lane] = bb;
        __syncthreads();
        if (w == 0) {
            pp[oA * 64 + lane] = redA[0][lane] + redA[1][lane] + redA[2][lane] + redA[3][lane];
            pp[oB * 64 + lane] = redB[0][lane] + redB[1][lane] + redB[2][lane] + redB[3][lane];
        }
    }

    // ---------------- Phase 1b: xw + u (all blocks, 12 rows each) ----------
    for (int i = tid; i < 4096; i += 256)
        sWt[(i & 63) * 65 + (i >> 6)] = gat_w[i];
    __syncthreads();
    const float att1 = gat_att[lane];
#pragma unroll
    for (int rr = 0; rr < 3; ++rr) {
        const int n = b * 12 + rr * 4 + w;
        const float* xr = (n < D_N) ? (c_emb + (size_t)c_it[n] * F_N)
                                    : (m_emb + (size_t)m_it[n - D_N] * F_N);
        const float rowv = xr[lane];
        float acc = 0.f;
#pragma unroll
        for (int j = 0; j < 64; ++j)
            acc += __shfl(rowv, j, 64) * sWt[j * 65 + lane];
        xw[(size_t)n * F_N + lane] = acc;
        float p = wred_sum(acc * att1);
        if (lane == 0) u[n] = p * L2E;     // log2-domain logits
    }
    if (b == 96 && w == 0) {               // w2[j] = sum_k att2[k]*W[k][j]
        float s = 0.f;
#pragma unroll
        for (int k = 0; k < 64; ++k)
            s += gat_att[64 + k] * sWt[lane * 65 + k];
        w2g[lane] = s;
    }

    gbar(&bar[0]);

    // ---------------- Phase 2: per-edge softmax scalars (4 edges/block) ----
    const int e = b * 4 + w;
    float w1a_reg, w2a_reg;
    {
        const float v = wred_sum(hattr[(size_t)e * F_N + lane] * w2g[lane]) * L2E;
        float s = 0.f;
#pragma unroll
        for (int i = 0; i < 16; ++i) {
            float a = u[D_N + i * 64 + lane] + v;
            a = fmaxf(a, 0.2f * a);
            s += exp2f(a);
        }
        s = wred_sum(s);
        float a_self = u[e] + v;
        a_self = fmaxf(a_self, 0.2f * a_self);
        const float ex_self = exp2f(a_self);
        const float denom = s + ex_self;
        const float asel = ex_self / denom;
        const float rd = 1.f / (denom * (float)(M_N + 1));
        w1a_reg = asel * rd * ex_self;
        w2a_reg = (1.f - asel) * rd * ex_self;
        if (lane == 0) {
            vS[e]  = v;
            c1f[e] = asel * rd;
            c2f[e] = (1.f - asel) * rd;
        }
    }

    gbar(&bar[1]);

    // ---------------- Phase 3: g-weights + partial matvec ------------------
    for (int i = tid; i < 512; i += 256) {
        sEdgeV[i] = vS[i]; sEdgeC1[i] = c1f[i]; sEdgeC2[i] = c2f[i];
    }
    __syncthreads();
    {
        const int mi = tid >> 5, l32 = tid & 31;     // 8 meds/block, 32 thr/med
        const int m = b * 8 + mi;
        const float um = u[D_N + m];
        float gA = 0.f, gB = 0.f;
#pragma unroll 4
        for (int i = 0; i < 16; ++i) {
            int ee = i * 32 + l32;
            float a = um + sEdgeV[ee];
            a = fmaxf(a, 0.2f * a);
            float ex = exp2f(a);
            gA += sEdgeC1[ee] * ex;
            gB += sEdgeC2[ee] * ex;
        }
#pragma unroll
        for (int off = 16; off > 0; off >>= 1) {
            gA += __shfl_xor(gA, off, 64);
            gB += __shfl_xor(gB, off, 64);
        }
        if (l32 == 0) { sGA[mi] = gA; sGB[mi] = gB; }
    }
    __syncthreads();
    {
        const float x0 = xw[(size_t)(D_N + b * 8 + 2 * w) * F_N + lane];
        const float x1 = xw[(size_t)(D_N + b * 8 + 2 * w + 1) * F_N + lane];
        const float xe = xw[(size_t)e * F_N + lane];
        float a1 = sGA[2 * w] * x0 + sGA[2 * w + 1] * x1 + w1a_reg * xe;
        float a2 = sGB[2 * w] * x0 + sGB[2 * w + 1] * x1 + w2a_reg * xe;
        redA[w][lane] = a1; redB[w][lane] = a2;
    }
    __syncthreads();
    if (w == 0) {
        ps[b * 128 + lane]      = redA[0][lane] + redA[1][lane] + redA[2][lane] + redA[3][lane];
        ps[b * 128 + 64 + lane] = redB[0][lane] + redB[1][lane] + redB[2][lane] + redB[3][lane];
    }

    // ---------------- last-done election -----------------------------------
    __threadfence();
    __syncthreads();
    if (tid == 0) {
        int old = __hip_atomic_fetch_add(&bar[2], 1, __ATOMIC_ACQ_REL, __HIP_MEMORY_SCOPE_AGENT);
        sIsLast = (old == GRID_B - 1);
    }
    __syncthreads();
    if (!sIsLast) return;

    // ---------------- Phase 4: finisher block ------------------------------
    {
        float a = 0.f, bb = 0.f;
        for (int i = 0; i < 32; ++i) {
            int blk = w * 32 + i;
            a  += ps[blk * 128 + lane];
            bb += ps[blk * 128 + 64 + lane];
        }
        redA[w][lane] = a; redB[w][lane] = bb;
    }
    __syncthreads();
    if (w == 0) {
        sS1[lane] = redA[0][lane] + redA[1][lane] + redA[2][lane] + redA[3][lane];
        sS2[lane] = (redB[0][lane] + redB[1][lane] + redB[2][lane] + redB[3][lane]) * (1.f / (float)D_N);
    } else if (w == 1) {
        float p0 = 0.f, mc = 0.f;
        for (int i = 0; i < 32; ++i) { p0 += pp[i * 64 + lane]; mc += pp[(32 + i) * 64 + lane]; }
        sP0[lane] = p0; sMC[lane] = mc * (1.f / (float)D_N);
    } else if (w == 2) {
        float p1 = 0.f;
        for (int i = 0; i < 64; ++i) p1 += pp[(64 + i) * 64 + lane];
        sP1[lane] = p1;
    } else {
        float mm = 0.f;
        for (int i = 0; i < 64; ++i) mm += pp[(128 + i) * 64 + lane];
        sMM[lane] = mm * (1.f / (float)M_N);
    }
    __syncthreads();
    if (tid < 64) {
        float dia = conv_b[lane], med = conv_b[lane];
#pragma unroll 8
        for (int j = 0; j < 64; ++j) {
            dia += sMC[j] * conv_w[lane * 64 + j];
            med += sMM[j] * conv_w[lane * 64 + j];
        }
        sRepD[lane]      = sS1[lane] + (float)D_N * gat_b[lane];
        sRepD[64 + lane] = (float)D_N * dia;
        sRepM[lane]      = sS2[lane] + (float)M_N * gat_b[lane];
        sRepM[64 + lane] = (float)M_N * med;
    }
    __syncthreads();
    if (tid < 64) {
        float o1 = sP0[lane], o2 = sP1[lane];
#pragma unroll 8
        for (int j = 0; j < 128; ++j) {
            o1 += sRepD[j] * lin_w[lane * 128 + j];
            o2 += sRepM[j] * lin_w[lane * 128 + j];
        }
        out[lane] = o1;
        out[64 + lane] = o2;
    }
}

extern "C" void kernel_launch(void* const* d_in, const int* in_sizes, int n_in,
                              void* d_out, int out_size, void* d_ws, size_t ws_size,
                              hipStream_t stream) {
    const int*   c_it    = (const int*)d_in[0];
    const int*   m_it    = (const int*)d_in[1];
    const float* c_emb   = (const float*)d_in[2];
    const float* m_emb   = (const float*)d_in[3];
    const float* pe0     = (const float*)d_in[4];
    const float* pe1     = (const float*)d_in[5];
    const float* conv_w  = (const float*)d_in[6];
    const float* conv_b  = (const float*)d_in[7];
    const float* gat_w   = (const float*)d_in[8];
    const float* gat_b   = (const float*)d_in[9];
    const float* gat_att = (const float*)d_in[10];
    const float* hattr   = (const float*)d_in[11];
    const float* lin_w   = (const float*)d_in[12];
    float* out = (float*)d_out;

    int*   bar  = (int*)d_ws;
    float* base = (float*)((char*)d_ws + 64);
    float* xw   = base;                         // 1536*64
    float* u    = xw + (D_N + M_N) * F_N;       // 1536
    float* w2g  = u + (D_N + M_N);              // 64
    float* vS   = w2g + 64;                     // 512
    float* c1f  = vS + D_N;                     // 512
    float* c2f  = c1f + D_N;                    // 512
    float* w1a  = c2f + D_N;                    // 512 (unused slots kept for layout)
    float* w2a  = w1a + D_N;                    // 512
    float* pp   = w2a + D_N;                    // 192*64
    float* ps   = pp + 192 * 64;                // 128*128

    hipMemsetAsync(d_ws, 0, 16, stream);        // zero barrier counters every call
    k_all<<<GRID_B, 256, 0, stream>>>(c_it, m_it, c_emb, m_emb, pe0, pe1,
                                      conv_w, conv_b, gat_w, gat_b, gat_att,
                                      hattr, lin_w, bar, xw, u, w2g,
                                      vS, c1f, c2f, w1a, w2a, pp, ps, out);
}

// Round 6
// 28.786 us; speedup vs baseline: 1.8657x; 1.8657x over previous
//
#include <hip/hip_runtime.h>
#include <hip/hip_bf16.h>

#define D_N 512
#define M_N 1024
#define F_N 64
#define L2E 1.442695041f

__device__ __forceinline__ float wred_sum(float p) {
#pragma unroll
    for (int off = 32; off > 0; off >>= 1) p += __shfl_xor(p, off, 64);
    return p;
}

// q[lane] = sum_k att[k] * W[k][lane]  (one wave; deterministic, shared by K1/K2)
__device__ __forceinline__ float proj_col(const float* __restrict__ gw,
                                          const float* __restrict__ att,
                                          int lane) {
    float acc = 0.f;
#pragma unroll
    for (int k = 0; k < 64; ++k)
        acc += att[k] * gw[k * 64 + lane];
    return acc;
}

// serial 64-dot of a global row with an LDS 64-vector (float4 path).
// MUST be bit-identical wherever u is recomputed (K1 umed vs K2 sU).
__device__ __forceinline__ float dot64(const float* __restrict__ row,
                                       const float* __restrict__ q) {
    const float4* r4 = (const float4*)row;
    const float4* q4 = (const float4*)q;
    float a0 = 0.f, a1 = 0.f, a2 = 0.f, a3 = 0.f;
#pragma unroll
    for (int i = 0; i < 16; ++i) {
        float4 x = r4[i], y = q4[i];
        a0 += x.x * y.x; a1 += x.y * y.y; a2 += x.z * y.z; a3 += x.w * y.w;
    }
    return (a0 + a1) + (a2 + a3);
}

// ---------------------------------------------------------------------------
// K1: blocks 0..63  : 8 edges each (wave per edge). Recompute q1,q2, u_med[1024]
//                     in-block; per-edge softmax denominator -> scalars.
//     blocks 64..111: partial gathers. pp: P0[0,16) MC[16,32) P1[32,64) MM[64,96)
// ---------------------------------------------------------------------------
__global__ __launch_bounds__(512) void k1(
    const int* __restrict__ c_it, const int* __restrict__ m_it,
    const float* __restrict__ c_emb, const float* __restrict__ m_emb,
    const float* __restrict__ pe0, const float* __restrict__ pe1,
    const float* __restrict__ gat_w, const float* __restrict__ gat_att,
    const float* __restrict__ hattr,
    float* __restrict__ vS, float* __restrict__ c1f, float* __restrict__ c2f,
    float* __restrict__ w1s, float* __restrict__ w2s, float* __restrict__ pp)
{
    __shared__ __align__(16) float q1s[64];
    __shared__ __align__(16) float q2s[64];
    __shared__ float umed[M_N];
    __shared__ float redA[8][64], redB[8][64];
    const int b = blockIdx.x, tid = threadIdx.x;
    const int w = tid >> 6, lane = tid & 63;

    if (b < 64) {
        if (w == 0) q1s[lane] = proj_col(gat_w, gat_att, lane);
        else if (w == 1) q2s[lane] = proj_col(gat_w, gat_att + 64, lane);
        __syncthreads();
#pragma unroll
        for (int i = 0; i < 2; ++i) {
            int m = tid + i * 512;
            umed[m] = L2E * dot64(m_emb + (size_t)m_it[m] * F_N, q1s);
        }
        __syncthreads();
        const int e = b * 8 + w;
        const float v  = L2E * wred_sum(hattr[(size_t)e * F_N + lane] * q2s[lane]);
        const float us = L2E * wred_sum(c_emb[(size_t)c_it[e] * F_N + lane] * q1s[lane]);
        float s = 0.f;
#pragma unroll
        for (int i = 0; i < 16; ++i) {
            float a = umed[i * 64 + lane] + v;
            a = fmaxf(a, 0.2f * a);
            s += exp2f(a);
        }
        s = wred_sum(s);
        float asf = us + v; asf = fmaxf(asf, 0.2f * asf);
        const float exs = exp2f(asf);
        const float denom = s + exs;
        const float asel = exs / denom;
        const float rd = 1.f / (denom * (float)(M_N + 1));
        if (lane == 0) {
            vS[e]  = v;
            c1f[e] = asel * rd;
            c2f[e] = (1.f - asel) * rd;
            w1s[e] = asel * rd * exs;
            w2s[e] = (1.f - asel) * rd * exs;
        }
    } else {
        const int g = b - 64;
        const int* idx; const float* ta; const float* tb;
        int base_r, oA, oB;
        if (g < 16) { idx = c_it; ta = pe0; tb = c_emb; base_r = g * 32; oA = g; oB = 16 + g; }
        else { int g2 = g - 16; idx = m_it; ta = pe1; tb = m_emb; base_r = g2 * 32; oA = 32 + g2; oB = 64 + g2; }
        const int r0 = base_r + w * 4;
        float a = 0.f, bb = 0.f;
#pragma unroll
        for (int j = 0; j < 4; ++j) {
            int r = idx[r0 + j];
            a  += ta[(size_t)r * F_N + lane];
            bb += tb[(size_t)r * F_N + lane];
        }
        redA[w][lane] = a; redB[w][lane] = bb;
        __syncthreads();
        if (w == 0) {
            float sa = 0.f, sbv = 0.f;
#pragma unroll
            for (int i = 0; i < 8; ++i) { sa += redA[i][lane]; sbv += redB[i][lane]; }
            pp[oA * 64 + lane] = sa;
            pp[oB * 64 + lane] = sbv;
        }
    }
}

// ---------------------------------------------------------------------------
// K2: blocks 0..31 : 32 meds each. g1/g2 per med (sum over 512 edges), then
//                    embedding-space weighted sums -> e1p/e2p partials.
//     blocks 32..35: self terms: sum_e w1s[e]*c_emb_row[e] -> e1dp/e2dp.
// ---------------------------------------------------------------------------
__global__ __launch_bounds__(512) void k2(
    const int* __restrict__ c_it, const int* __restrict__ m_it,
    const float* __restrict__ c_emb, const float* __restrict__ m_emb,
    const float* __restrict__ gat_w, const float* __restrict__ gat_att,
    const float* __restrict__ vS, const float* __restrict__ c1f,
    const float* __restrict__ c2f, const float* __restrict__ w1s,
    const float* __restrict__ w2s,
    float* __restrict__ e1p, float* __restrict__ e2p,
    float* __restrict__ e1dp, float* __restrict__ e2dp)
{
    __shared__ float sV[D_N], sC1[D_N], sC2[D_N];
    __shared__ __align__(16) float q1s[64];
    __shared__ float sU[32], sG1[32], sG2[32];
    __shared__ float redA[8][64], redB[8][64];
    const int b = blockIdx.x, tid = threadIdx.x;
    const int w = tid >> 6, lane = tid & 63;

    if (b < 32) {
        if (w == 0) q1s[lane] = proj_col(gat_w, gat_att, lane);
        if (tid < 512) { sV[tid] = vS[tid]; sC1[tid] = c1f[tid]; sC2[tid] = c2f[tid]; }
        __syncthreads();
        if (tid < 32)
            sU[tid] = L2E * dot64(m_emb + (size_t)m_it[b * 32 + tid] * F_N, q1s);
        __syncthreads();
        const int mi = tid >> 4, l16 = tid & 15;
        const float um = sU[mi];
        float gA = 0.f, gB = 0.f;
#pragma unroll 4
        for (int i = 0; i < 32; ++i) {
            int e = l16 + i * 16;
            float a = um + sV[e];
            a = fmaxf(a, 0.2f * a);
            float ex = exp2f(a);
            gA += sC1[e] * ex;
            gB += sC2[e] * ex;
        }
#pragma unroll
        for (int off = 1; off < 16; off <<= 1) {
            gA += __shfl_xor(gA, off, 64);
            gB += __shfl_xor(gB, off, 64);
        }
        if (l16 == 0) { sG1[mi] = gA; sG2[mi] = gB; }
        __syncthreads();
        float a1 = 0.f, a2 = 0.f;
#pragma unroll
        for (int j = 0; j < 4; ++j) {
            int ml = w * 4 + j;
            float x = m_emb[(size_t)m_it[b * 32 + ml] * F_N + lane];
            a1 += sG1[ml] * x;
            a2 += sG2[ml] * x;
        }
        redA[w][lane] = a1; redB[w][lane] = a2;
        __syncthreads();
        if (w == 0) {
            float sa = 0.f, sbv = 0.f;
#pragma unroll
            for (int i = 0; i < 8; ++i) { sa += redA[i][lane]; sbv += redB[i][lane]; }
            e1p[b * 64 + lane] = sa;
            e2p[b * 64 + lane] = sbv;
        }
    } else {
        const int sb = b - 32;
        float a1 = 0.f, a2 = 0.f;
#pragma unroll
        for (int j = 0; j < 16; ++j) {
            int e = sb * 128 + w * 16 + j;
            float x = c_emb[(size_t)c_it[e] * F_N + lane];
            a1 += w1s[e] * x;
            a2 += w2s[e] * x;
        }
        redA[w][lane] = a1; redB[w][lane] = a2;
        __syncthreads();
        if (w == 0) {
            float sa = 0.f, sbv = 0.f;
#pragma unroll
            for (int i = 0; i < 8; ++i) { sa += redA[i][lane]; sbv += redB[i][lane]; }
            e1dp[sb * 64 + lane] = sa;
            e2dp[sb * 64 + lane] = sbv;
        }
    }
}

// ---------------------------------------------------------------------------
// K3: single-block finisher: fold partials, S = E @ W^T, conv matvecs, lin.
// ---------------------------------------------------------------------------
__global__ __launch_bounds__(256) void k3(
    const float* __restrict__ conv_w, const float* __restrict__ conv_b,
    const float* __restrict__ gat_w, const float* __restrict__ gat_b,
    const float* __restrict__ lin_w,
    const float* __restrict__ pp,
    const float* __restrict__ e1p, const float* __restrict__ e2p,
    const float* __restrict__ e1dp, const float* __restrict__ e2dp,
    float* __restrict__ out)
{
    __shared__ float sE1[64], sE2[64], sP0[64], sP1[64], sMC[64], sMM[64];
    __shared__ float sS1[64], sS2[64];
    __shared__ float sRepD[128], sRepM[128];
    __shared__ float sWt[64 * 65];
    __shared__ float sLt[128 * 65];
    const int tid = threadIdx.x, w = tid >> 6, lane = tid & 63;

    if (w == 0) {
        float a = 0.f;
#pragma unroll
        for (int i = 0; i < 32; ++i) a += e1p[i * 64 + lane];
#pragma unroll
        for (int i = 0; i < 4; ++i) a += e1dp[i * 64 + lane];
        sE1[lane] = a;
    } else if (w == 1) {
        float a = 0.f;
#pragma unroll
        for (int i = 0; i < 32; ++i) a += e2p[i * 64 + lane];
#pragma unroll
        for (int i = 0; i < 4; ++i) a += e2dp[i * 64 + lane];
        sE2[lane] = a;
    } else if (w == 2) {
        float a = 0.f, c = 0.f;
#pragma unroll
        for (int i = 0; i < 16; ++i) { a += pp[i * 64 + lane]; c += pp[(16 + i) * 64 + lane]; }
        sP0[lane] = a; sMC[lane] = c * (1.f / (float)D_N);
    } else {
        float a = 0.f, c = 0.f;
#pragma unroll
        for (int i = 0; i < 32; ++i) { a += pp[(32 + i) * 64 + lane]; c += pp[(64 + i) * 64 + lane]; }
        sP1[lane] = a; sMM[lane] = c * (1.f / (float)M_N);
    }
    for (int i = tid; i < 4096; i += 256)
        sWt[(i & 63) * 65 + (i >> 6)] = gat_w[i];          // sWt[j*65+k]=W[k][j]
    for (int i = tid; i < 8192; i += 256) {
        int k = i >> 7, j = i & 127;
        sLt[j * 65 + k] = lin_w[i];                        // sLt[j*65+k]=lin_w[k][j]
    }
    __syncthreads();
    if (tid < 64) {
        float s1 = 0.f, s2 = 0.f;
#pragma unroll 8
        for (int j = 0; j < 64; ++j) {
            s1 += sE1[j] * sWt[j * 65 + lane];
            s2 += sE2[j] * sWt[j * 65 + lane];
        }
        sS1[lane] = s1;
        sS2[lane] = s2 * (1.f / (float)D_N);
    }
    __syncthreads();
    for (int i = tid; i < 4096; i += 256)
        sWt[(i & 63) * 65 + (i >> 6)] = conv_w[i];
    __syncthreads();
    if (tid < 64) {
        float dia = conv_b[lane], med = conv_b[lane];
#pragma unroll 8
        for (int j = 0; j < 64; ++j) {
            dia += sMC[j] * sWt[j * 65 + lane];
            med += sMM[j] * sWt[j * 65 + lane];
        }
        sRepD[lane]      = sS1[lane] + (float)D_N * gat_b[lane];
        sRepD[64 + lane] = (float)D_N * dia;
        sRepM[lane]      = sS2[lane] + (float)M_N * gat_b[lane];
        sRepM[64 + lane] = (float)M_N * med;
    }
    __syncthreads();
    if (tid < 64) {
        float o1 = sP0[lane], o2 = sP1[lane];
#pragma unroll 8
        for (int j = 0; j < 128; ++j) {
            o1 += sRepD[j] * sLt[j * 65 + lane];
            o2 += sRepM[j] * sLt[j * 65 + lane];
        }
        out[lane] = o1;
        out[64 + lane] = o2;
    }
}

extern "C" void kernel_launch(void* const* d_in, const int* in_sizes, int n_in,
                              void* d_out, int out_size, void* d_ws, size_t ws_size,
                              hipStream_t stream) {
    const int*   c_it    = (const int*)d_in[0];
    const int*   m_it    = (const int*)d_in[1];
    const float* c_emb   = (const float*)d_in[2];
    const float* m_emb   = (const float*)d_in[3];
    const float* pe0     = (const float*)d_in[4];
    const float* pe1     = (const float*)d_in[5];
    const float* conv_w  = (const float*)d_in[6];
    const float* conv_b  = (const float*)d_in[7];
    const float* gat_w   = (const float*)d_in[8];
    const float* gat_b   = (const float*)d_in[9];
    const float* gat_att = (const float*)d_in[10];
    const float* hattr   = (const float*)d_in[11];
    const float* lin_w   = (const float*)d_in[12];
    float* out = (float*)d_out;

    float* ws   = (float*)d_ws;
    float* vS   = ws;                 // 512
    float* c1f  = vS + D_N;           // 512
    float* c2f  = c1f + D_N;          // 512
    float* w1s  = c2f + D_N;          // 512
    float* w2s  = w1s + D_N;          // 512
    float* pp   = w2s + D_N;          // 96*64
    float* e1p  = pp + 96 * 64;       // 32*64
    float* e2p  = e1p + 32 * 64;      // 32*64
    float* e1dp = e2p + 32 * 64;      // 4*64
    float* e2dp = e1dp + 4 * 64;      // 4*64

    k1<<<112, 512, 0, stream>>>(c_it, m_it, c_emb, m_emb, pe0, pe1,
                                gat_w, gat_att, hattr,
                                vS, c1f, c2f, w1s, w2s, pp);
    k2<<<36, 512, 0, stream>>>(c_it, m_it, c_emb, m_emb, gat_w, gat_att,
                               vS, c1f, c2f, w1s, w2s,
                               e1p, e2p, e1dp, e2dp);
    k3<<<1, 256, 0, stream>>>(conv_w, conv_b, gat_w, gat_b, lin_w,
                              pp, e1p, e2p, e1dp, e2dp, out);
}